// Round 1
// baseline (58.219 us; speedup 1.0000x reference)
//
#include <hip/hip_runtime.h>

#define BB 16
#define TT 1024
#define HH 14
#define WW 14
#define CC 16

constexpr int   FL4_PER_T     = HH * WW * CC / 4;        // 784 float4 per t-slab
constexpr int   FL4_PER_BATCH = TT * FL4_PER_T;          // 802816
constexpr int   BLOCKS_PER_B  = 98;                      // 802816 / 98 = 8192
constexpr int   FL4_PER_BLOCK = FL4_PER_BATCH / BLOCKS_PER_B;  // 8192
constexpr int   THREADS       = 256;
constexpr int   ITERS         = FL4_PER_BLOCK / THREADS; // 32

#define EPSF      1e-7f
#define INV_H     (1.0f / 14.0f)
#define LN_INV_H  (-2.63905732962f)   /* ln(1/14) */

__global__ __launch_bounds__(THREADS)
void ttv_sums_kernel(const float* __restrict__ cam,
                     const int*   __restrict__ length,
                     float* __restrict__ g_act,   // [B*C]
                     float* __restrict__ g_blk,   // [B*C]
                     float* __restrict__ g_kl)    // [1]
{
    const int b   = blockIdx.x / BLOCKS_PER_B;
    const int bb  = blockIdx.x % BLOCKS_PER_B;
    const int len = length[b];

    const float4* __restrict__ base =
        reinterpret_cast<const float4*>(cam + (size_t)b * (size_t)FL4_PER_BATCH * 4u);

    int v = bb * FL4_PER_BLOCK + (int)threadIdx.x;   // float4 index within batch
    // v % 4 is constant per thread (stride 256), so this thread always touches
    // channels c_base .. c_base+3
    float a0 = 0.f, a1 = 0.f, a2 = 0.f, a3 = 0.f;    // active sums (4 channels)
    float b0 = 0.f, b1 = 0.f, b2 = 0.f, b3 = 0.f;    // blank sums
    float kl = 0.f;

    #pragma unroll 4
    for (int it = 0; it < ITERS; ++it, v += THREADS) {
        float4 x = base[v];
        int t = v / FL4_PER_T;
        if (t < len) {
            a0 += x.x; a1 += x.y; a2 += x.z; a3 += x.w;
            float l0 = __logf(fminf(fmaxf(x.x, EPSF), 1.0f));
            float l1 = __logf(fminf(fmaxf(x.y, EPSF), 1.0f));
            float l2 = __logf(fminf(fmaxf(x.z, EPSF), 1.0f));
            float l3 = __logf(fminf(fmaxf(x.w, EPSF), 1.0f));
            kl += INV_H * (4.0f * LN_INV_H - (l0 + l1 + l2 + l3));
        } else {
            b0 += x.x; b1 += x.y; b2 += x.z; b3 += x.w;
        }
    }

    // --- wave-level reduce ---
    // channel-group reduce: sum the 16 lanes of this wave that share (lane & 3)
    #pragma unroll
    for (int off = 4; off <= 32; off <<= 1) {
        a0 += __shfl_xor(a0, off); a1 += __shfl_xor(a1, off);
        a2 += __shfl_xor(a2, off); a3 += __shfl_xor(a3, off);
        b0 += __shfl_xor(b0, off); b1 += __shfl_xor(b1, off);
        b2 += __shfl_xor(b2, off); b3 += __shfl_xor(b3, off);
    }
    // kl: full 64-lane reduce
    #pragma unroll
    for (int off = 1; off <= 32; off <<= 1) kl += __shfl_xor(kl, off);

    __shared__ float s_act[CC];
    __shared__ float s_blk[CC];
    __shared__ float s_kl;
    if (threadIdx.x < CC) { s_act[threadIdx.x] = 0.f; s_blk[threadIdx.x] = 0.f; }
    if (threadIdx.x == 0) s_kl = 0.f;
    __syncthreads();

    const int lane = (int)(threadIdx.x & 63u);
    if (lane < 4) {
        const int cb = lane * 4;   // lanes 0..3 hold channel groups 0,4,8,12
        atomicAdd(&s_act[cb + 0], a0); atomicAdd(&s_act[cb + 1], a1);
        atomicAdd(&s_act[cb + 2], a2); atomicAdd(&s_act[cb + 3], a3);
        atomicAdd(&s_blk[cb + 0], b0); atomicAdd(&s_blk[cb + 1], b1);
        atomicAdd(&s_blk[cb + 2], b2); atomicAdd(&s_blk[cb + 3], b3);
    }
    if (lane == 0) atomicAdd(&s_kl, kl);
    __syncthreads();

    if (threadIdx.x < CC) {
        atomicAdd(&g_act[b * CC + (int)threadIdx.x], s_act[threadIdx.x]);
    } else if (threadIdx.x < 2 * CC) {
        atomicAdd(&g_blk[b * CC + (int)threadIdx.x - CC], s_blk[threadIdx.x - CC]);
    } else if (threadIdx.x == 2 * CC) {
        atomicAdd(g_kl, s_kl);
    }
}

__global__ __launch_bounds__(THREADS)
void ttv_finalize_kernel(const float* __restrict__ g_act,
                         const float* __restrict__ g_blk,
                         const float* __restrict__ g_kl,
                         const float* __restrict__ count,
                         float* __restrict__ out)
{
    const int tid = (int)threadIdx.x;     // tid = b*16 + c  (tid < 256)
    const int b = tid >> 4;
    const int c = tid & 15;

    const float as  = g_act[tid];
    const float bs  = g_blk[tid];
    const float cnt = count[tid];

    // huber(count, active_sum), DELTA = 1
    float ea = fabsf(as - cnt);
    float qa = fminf(ea, 1.0f);
    float ha = 0.5f * qa * qa + (ea - qa);
    // huber(0, blank_sum)
    float eb = fabsf(bs);
    float qb = fminf(eb, 1.0f);
    float hb = 0.5f * qb * qb + (eb - qb);

    float h = ha + hb;
    // threads b*16 .. b*16+15 sit in the same wave (wave = 64) -> shuffle-mean over C
    #pragma unroll
    for (int off = 1; off < 16; off <<= 1) h += __shfl_xor(h, off);

    if (c == 0) {
        const float kl_loss = g_kl[0] * (0.1f / (float)(BB * TT * HH * WW));
        out[b] = h * (1.0f / 16.0f) + kl_loss;
    }
}

extern "C" void kernel_launch(void* const* d_in, const int* in_sizes, int n_in,
                              void* d_out, int out_size, void* d_ws, size_t ws_size,
                              hipStream_t stream)
{
    const float* cam    = (const float*)d_in[0];
    const float* count  = (const float*)d_in[1];
    const int*   length = (const int*)d_in[2];
    float* out = (float*)d_out;

    float* g_act = (float*)d_ws;          // 256 floats
    float* g_blk = g_act + BB * CC;       // 256 floats
    float* g_kl  = g_blk + BB * CC;       // 1 float

    hipMemsetAsync(d_ws, 0, (size_t)(2 * BB * CC + 1) * sizeof(float), stream);

    ttv_sums_kernel<<<BB * BLOCKS_PER_B, THREADS, 0, stream>>>(cam, length, g_act, g_blk, g_kl);
    ttv_finalize_kernel<<<1, THREADS, 0, stream>>>(g_act, g_blk, g_kl, count, out);
}

// Round 2
// 45.602 us; speedup vs baseline: 1.2767x; 1.2767x over previous
//
#include <hip/hip_runtime.h>

#define BB 16
#define TT 1024
#define HH 14
#define WW 14
#define CC 16

constexpr int FL4_PER_T     = HH * WW * CC / 4;          // 784
constexpr int FL4_PER_BATCH = TT * FL4_PER_T;            // 802816
constexpr int CHUNKS_PER_B  = 64;
constexpr int FL4_PER_CHUNK = FL4_PER_BATCH / CHUNKS_PER_B; // 12544
constexpr int T_PER_CHUNK   = TT / CHUNKS_PER_B;         // 16
constexpr int THREADS       = 256;
constexpr int ITERS         = FL4_PER_CHUNK / THREADS;   // 49
constexpr int NBLOCKS       = BB * CHUNKS_PER_B;         // 1024

// d_ws layout (floats): act partials [0,16384) , blk partials [16384,32768),
// kl partials [32768, 33792)
constexpr int WS_BLK_OFF = NBLOCKS * CC;                 // 16384
constexpr int WS_KL_OFF  = 2 * NBLOCKS * CC;             // 32768

#define EPSF      1e-7f
#define INV_H     (1.0f / 14.0f)
#define LN_INV_H  (-2.63905732962f)   /* ln(1/14) */

__device__ __forceinline__ void active_body(const float4 x,
    float& a0, float& a1, float& a2, float& a3, float& kl)
{
    a0 += x.x; a1 += x.y; a2 += x.z; a3 += x.w;
    float l0 = __logf(fminf(fmaxf(x.x, EPSF), 1.0f));
    float l1 = __logf(fminf(fmaxf(x.y, EPSF), 1.0f));
    float l2 = __logf(fminf(fmaxf(x.z, EPSF), 1.0f));
    float l3 = __logf(fminf(fmaxf(x.w, EPSF), 1.0f));
    kl += 4.0f * LN_INV_H - (l0 + l1 + l2 + l3);
}

__global__ __launch_bounds__(THREADS)
void ttv_sums_kernel(const float* __restrict__ cam,
                     const int*   __restrict__ length,
                     float* __restrict__ part)
{
    const int bid   = (int)blockIdx.x;
    const int b     = bid >> 6;          // / CHUNKS_PER_B
    const int chunk = bid & 63;
    const int len   = length[b];
    const int rel   = len - chunk * T_PER_CHUNK;  // active iff t_local < rel

    const float4* __restrict__ base =
        reinterpret_cast<const float4*>(cam) + (size_t)bid * FL4_PER_CHUNK;

    float a0 = 0.f, a1 = 0.f, a2 = 0.f, a3 = 0.f;   // active channel-group sums
    float q0 = 0.f, q1 = 0.f, q2 = 0.f, q3 = 0.f;   // blank channel-group sums
    float kl = 0.f;

    int idx = (int)threadIdx.x;   // idx % 4 constant per thread -> fixed 4-channel group

    if (rel >= T_PER_CHUNK) {
        // fully active chunk: no division, no branch
        #pragma unroll 4
        for (int it = 0; it < ITERS; ++it, idx += THREADS) {
            float4 x = base[idx];
            active_body(x, a0, a1, a2, a3, kl);
        }
    } else if (rel <= 0) {
        // fully blank chunk: pure streaming adds
        #pragma unroll 4
        for (int it = 0; it < ITERS; ++it, idx += THREADS) {
            float4 x = base[idx];
            q0 += x.x; q1 += x.y; q2 += x.z; q3 += x.w;
        }
    } else {
        // mixed chunk (at most one per batch)
        #pragma unroll 4
        for (int it = 0; it < ITERS; ++it, idx += THREADS) {
            float4 x = base[idx];
            int tl = idx / FL4_PER_T;   // 0..15
            if (tl < rel) {
                active_body(x, a0, a1, a2, a3, kl);
            } else {
                q0 += x.x; q1 += x.y; q2 += x.z; q3 += x.w;
            }
        }
    }

    // wave-level reduce: sum lanes sharing (lane & 3) -> lanes 0..3 hold
    // channel groups {0-3},{4-7},{8-11},{12-15}
    #pragma unroll
    for (int off = 4; off <= 32; off <<= 1) {
        a0 += __shfl_xor(a0, off); a1 += __shfl_xor(a1, off);
        a2 += __shfl_xor(a2, off); a3 += __shfl_xor(a3, off);
        q0 += __shfl_xor(q0, off); q1 += __shfl_xor(q1, off);
        q2 += __shfl_xor(q2, off); q3 += __shfl_xor(q3, off);
    }
    #pragma unroll
    for (int off = 1; off <= 32; off <<= 1) kl += __shfl_xor(kl, off);

    __shared__ float s_red[2 * CC + 1];
    if (threadIdx.x < 2 * CC + 1) s_red[threadIdx.x] = 0.f;
    __syncthreads();

    const int lane = (int)(threadIdx.x & 63u);
    if (lane < 4) {
        const int cb = lane * 4;
        atomicAdd(&s_red[cb + 0], a0); atomicAdd(&s_red[cb + 1], a1);
        atomicAdd(&s_red[cb + 2], a2); atomicAdd(&s_red[cb + 3], a3);
        atomicAdd(&s_red[CC + cb + 0], q0); atomicAdd(&s_red[CC + cb + 1], q1);
        atomicAdd(&s_red[CC + cb + 2], q2); atomicAdd(&s_red[CC + cb + 3], q3);
    }
    if (lane == 0) atomicAdd(&s_red[2 * CC], kl * INV_H);
    __syncthreads();

    // write per-block partials (no global atomics)
    if (threadIdx.x < CC) {
        part[bid * CC + (int)threadIdx.x] = s_red[threadIdx.x];
    } else if (threadIdx.x < 2 * CC) {
        part[WS_BLK_OFF + bid * CC + (int)threadIdx.x - CC] = s_red[threadIdx.x];
    } else if (threadIdx.x == 2 * CC) {
        part[WS_KL_OFF + bid] = s_red[2 * CC];
    }
}

__global__ __launch_bounds__(THREADS)
void ttv_finalize_kernel(const float* __restrict__ part,
                         const float* __restrict__ count,
                         float* __restrict__ out)
{
    const int tid = (int)threadIdx.x;   // tid = b*16 + c
    const int b = tid >> 4;
    const int c = tid & 15;

    float as = 0.f, bs = 0.f;
    #pragma unroll
    for (int k = 0; k < CHUNKS_PER_B; ++k) {
        const int row = (b * CHUNKS_PER_B + k) * CC + c;
        as += part[row];
        bs += part[WS_BLK_OFF + row];
    }

    // kl: 1024 partials reduced by the whole block
    float kl = 0.f;
    #pragma unroll
    for (int k = tid; k < NBLOCKS; k += THREADS) kl += part[WS_KL_OFF + k];
    #pragma unroll
    for (int off = 1; off <= 32; off <<= 1) kl += __shfl_xor(kl, off);
    __shared__ float s_kl[4];
    if ((tid & 63) == 0) s_kl[tid >> 6] = kl;
    __syncthreads();
    const float klsum = s_kl[0] + s_kl[1] + s_kl[2] + s_kl[3];

    const float cnt = count[tid];
    // huber(count, active_sum), DELTA = 1
    float ea = fabsf(as - cnt);
    float qa = fminf(ea, 1.0f);
    float ha = 0.5f * qa * qa + (ea - qa);
    // huber(0, blank_sum)
    float eb = fabsf(bs);
    float qb = fminf(eb, 1.0f);
    float hb = 0.5f * qb * qb + (eb - qb);

    float h = ha + hb;
    #pragma unroll
    for (int off = 1; off < 16; off <<= 1) h += __shfl_xor(h, off);

    if (c == 0) {
        const float kl_loss = klsum * (0.1f / (float)(BB * TT * HH * WW));
        out[b] = h * (1.0f / 16.0f) + kl_loss;
    }
}

extern "C" void kernel_launch(void* const* d_in, const int* in_sizes, int n_in,
                              void* d_out, int out_size, void* d_ws, size_t ws_size,
                              hipStream_t stream)
{
    const float* cam    = (const float*)d_in[0];
    const float* count  = (const float*)d_in[1];
    const int*   length = (const int*)d_in[2];
    float* out  = (float*)d_out;
    float* part = (float*)d_ws;   // 33792 floats = 132 KB

    ttv_sums_kernel<<<NBLOCKS, THREADS, 0, stream>>>(cam, length, part);
    ttv_finalize_kernel<<<1, THREADS, 0, stream>>>(part, count, out);
}